// Round 16
// baseline (71.304 us; speedup 1.0000x reference)
//
#include <hip/hip_runtime.h>

#define BSZ 256
#define SEQ 2048
#define NT  64
#define KS  5.0f

#define CLT 8                     // steps per chunk
#define SC  (16 * CLT)            // steps per superchunk = 128
#define NG  (SEQ / SC)            // superchunks per sequence = 16

#define SROW  136                 // LDS bytes per (s,k) row: 64 f16 + 8 pad
#define SSLAB (16 * SROW + 8)     // LDS bytes per s-slab (16 runs) + pad
#define RWS   68                  // r/w LDS row stride in floats

typedef __fp16 half2_t __attribute__((ext_vector_type(2)));
typedef __fp16 half4_t __attribute__((ext_vector_type(4)));
typedef float  f32x4_t __attribute__((ext_vector_type(4)));
typedef int    int2_t  __attribute__((ext_vector_type(2)));

static __device__ __forceinline__ float wave_red_sum(float x) {
#pragma unroll
    for (int d = 1; d < 64; d <<= 1) x += __shfl_xor(x, d);
    return x;
}

// intra-quad xor-1 / xor-2 via DPP quad_perm (pure VALU, no LDS pipe)
static __device__ __forceinline__ float dpp_xor1(float v) {
    return __builtin_bit_cast(float,
        __builtin_amdgcn_update_dpp(0, __builtin_bit_cast(int, v), 0xB1, 0xF, 0xF, true));
}
static __device__ __forceinline__ float dpp_xor2(float v) {
    return __builtin_bit_cast(float,
        __builtin_amdgcn_update_dpp(0, __builtin_bit_cast(int, v), 0x4E, 0xF, 0xF, true));
}

static __device__ __forceinline__ half4_t pack4(float a, float b, float c, float d) {
    half2_t lo = __builtin_amdgcn_cvt_pkrtz(a, b);
    half2_t hi = __builtin_amdgcn_cvt_pkrtz(c, d);
    int2_t t;
    t.x = __builtin_bit_cast(int, lo);
    t.y = __builtin_bit_cast(int, hi);
    return __builtin_bit_cast(half4_t, t);
}

// ---------------------------------------------------------------------------
// Fat kernel. Blocks [0,BSZ): numerator. Blocks [BSZ,...): pass1 per
// (batch, superchunk): stage F->LDS coalesced; A-fragments built inline from
// trans (overlaps stage HBM wait); wave0 16 fwd runs, wave1 16 bwd runs
// (MFMA chains, no renorm — f32 range suffices, Cf = KS*popcount);
// epilogue: transposed junction reduction (quad per junction, DPP),
// fwd wave only; boundary r/w vectors to global.
// ---------------------------------------------------------------------------
__global__ __launch_bounds__(128) void crf_fat_kernel(
    const float* __restrict__ logits,
    const int*   __restrict__ tags,
    const int*   __restrict__ mask,
    const float* __restrict__ trans,
    const float* __restrict__ startT,
    const float* __restrict__ endT,
    float* __restrict__ rB,      // [BSZ][NG][64]
    float* __restrict__ wB,      // [BSZ][NG][64]
    float* __restrict__ Jpart,   // [BSZ][NG]
    float* __restrict__ numtrans)
{
    __shared__ __align__(16) unsigned char Flds[CLT * SSLAB];
    __shared__ int lmbits[16];

    if (blockIdx.x < BSZ) {
        // ---------------- numerator branch ----------------
        const int b   = blockIdx.x;
        const int tid = threadIdx.x;
        float* redf = (float*)Flds;
        int*   redi = (int*)(Flds + 512);

        const int*   __restrict__ tg = tags + (size_t)b * SEQ;
        const int*   __restrict__ mk = mask + (size_t)b * SEQ;
        const float* __restrict__ Lr = logits + (size_t)b * SEQ * NT;

        float acc = 0.0f;
        int   cnt = 0;
        for (int t = tid; t < SEQ; t += 128) {
            int mt  = mk[t];
            cnt += mt;
            int tgt = tg[t] * mt;
            if (t < SEQ - 1) {
                int m1 = mk[t + 1];
                acc += trans[tgt * NT + tg[t + 1] * m1] * (float)m1;
                acc += Lr[t * NT + tgt] * (float)mt;
            }
        }
        redf[tid] = acc;
        redi[tid] = cnt;
        __syncthreads();
        for (int off = 64; off > 0; off >>= 1) {
            if (tid < off) {
                redf[tid] += redf[tid + off];
                redi[tid] += redi[tid + off];
            }
            __syncthreads();
        }
        if (tid == 0) {
            int   last_idx = redi[0] - 1;
            int   m_last   = mk[SEQ - 1];
            int   tag0     = tg[0] * mk[0];
            int   last_tag = tg[last_idx] * mk[last_idx];
            float r = redf[0] + startT[tag0] + endT[last_tag];
            r += Lr[(size_t)(SEQ - 1) * NT + last_tag] * (float)m_last;
            numtrans[b] = r;
        }
        return;
    }

    // ---------------- pass1 branch ----------------
    const int blk  = blockIdx.x - BSZ;
    const int b    = blk / NG;
    const int g    = blk % NG;
    const int tid  = threadIdx.x;
    const bool fwd = (tid >> 6) == 0;
    const int lane = tid & 63;
    const int rlo  = lane & 15;     // run (sub-chunk) index
    const int h    = lane >> 4;

    // ---- stage F (f16) into LDS, coalesced, loads batched 8-deep ----
    const float* __restrict__ Lg = logits + ((size_t)b * SEQ + (size_t)g * SC) * NT;
#pragma unroll
    for (int hh = 0; hh < 2; ++hh) {
        f32x4_t xb[8];
#pragma unroll
        for (int jj = 0; jj < 8; ++jj) {
            int gci = (hh * 8 + jj) * 128 + tid;
            xb[jj] = *(const f32x4_t*)(Lg + (size_t)(gci >> 4) * NT + (gci & 15) * 4);
        }
#pragma unroll
        for (int jj = 0; jj < 8; ++jj) {
            int gci = (hh * 8 + jj) * 128 + tid;
            int row = gci >> 4;
            int col = gci & 15;
            int k   = row / CLT;
            int s   = row % CLT;
            half2_t p0 = __builtin_amdgcn_cvt_pkrtz(__expf(xb[jj][0] - KS), __expf(xb[jj][1] - KS));
            half2_t p1 = __builtin_amdgcn_cvt_pkrtz(__expf(xb[jj][2] - KS), __expf(xb[jj][3] - KS));
            int2_t w;
            w.x = __builtin_bit_cast(int, p0);
            w.y = __builtin_bit_cast(int, p1);
            *(int2_t*)(Flds + s * SSLAB + k * SROW + col * 8) = w;
        }
    }
    if (tid < 16) {
        const int* mk = mask + (size_t)b * SEQ + (size_t)g * SC + tid * CLT;
        int bits = 0;
#pragma unroll
        for (int s = 0; s < CLT; ++s) bits |= (mk[s] ? 1 : 0) << s;
        if (g == 0 && tid == 0) bits &= ~1;   // t=0 is the init, not a D-step
        lmbits[tid] = bits;
    }

    // ---- A fragments inline: fwd A = E^T, bwd A = E (overlaps stage wait)
    half4_t A[4][4];
#pragma unroll
    for (int q = 0; q < 4; ++q)
#pragma unroll
        for (int kc = 0; kc < 4; ++kc) {
            float e[4];
#pragma unroll
            for (int i = 0; i < 4; ++i) {
                int m = 16 * q + rlo;
                int k = 16 * kc + 4 * h + i;
                e[i] = __expf(fwd ? trans[k * NT + m] : trans[m * NT + k]);
            }
            A[q][kc] = pack4(e[0], e[1], e[2], e[3]);
        }

    __syncthreads();

    const int mbits = lmbits[rlo];
    f32x4_t V[4];
    float C = KS * (float)__builtin_popcount(mbits);   // Cf, no renorm needed
#pragma unroll
    for (int q = 0; q < 4; ++q)
#pragma unroll
        for (int i = 0; i < 4; ++i) V[q][i] = 1.0f;

    if (fwd && g == 0 && rlo == 0) {
        // true init for global chunk 0: alpha0 = start + em(t=0)
        float mx = -1e30f;
        f32x4_t al[4];
#pragma unroll
        for (int q = 0; q < 4; ++q) {
            f32x4_t em = *(const f32x4_t*)(logits + (size_t)b * SEQ * NT + 16 * q + 4 * h);
            f32x4_t st = *(const f32x4_t*)(startT + 16 * q + 4 * h);
#pragma unroll
            for (int i = 0; i < 4; ++i) {
                al[q][i] = st[i] + em[i];
                mx = fmaxf(mx, al[q][i]);
            }
        }
        mx = fmaxf(mx, __shfl_xor(mx, 16));
        mx = fmaxf(mx, __shfl_xor(mx, 32));
        C += mx;
#pragma unroll
        for (int q = 0; q < 4; ++q)
#pragma unroll
            for (int i = 0; i < 4; ++i) V[q][i] = __expf(al[q][i] - mx);
    }

    const unsigned char* Fbase = Flds + rlo * SROW + h * 8;

    if (fwd) {
#pragma unroll
        for (int s = 0; s < CLT; ++s) {
            half4_t Fh[4];
#pragma unroll
            for (int q = 0; q < 4; ++q)
                Fh[q] = *(const half4_t*)(Fbase + s * SSLAB + q * 32);
            half4_t Xh[4];
#pragma unroll
            for (int kc = 0; kc < 4; ++kc)
                Xh[kc] = pack4(V[kc][0], V[kc][1], V[kc][2], V[kc][3]);
            f32x4_t Y[4];
#pragma unroll
            for (int q = 0; q < 4; ++q) {
                f32x4_t a0 = {0.0f, 0.0f, 0.0f, 0.0f};
                f32x4_t a1 = {0.0f, 0.0f, 0.0f, 0.0f};
                a0 = __builtin_amdgcn_mfma_f32_16x16x16f16(A[q][0], Xh[0], a0, 0, 0, 0);
                a0 = __builtin_amdgcn_mfma_f32_16x16x16f16(A[q][1], Xh[1], a0, 0, 0, 0);
                a1 = __builtin_amdgcn_mfma_f32_16x16x16f16(A[q][2], Xh[2], a1, 0, 0, 0);
                a1 = __builtin_amdgcn_mfma_f32_16x16x16f16(A[q][3], Xh[3], a1, 0, 0, 0);
                Y[q] = a0 + a1;
            }
            int mt = (mbits >> s) & 1;
#pragma unroll
            for (int q = 0; q < 4; ++q)
#pragma unroll
                for (int i = 0; i < 4; ++i) {
                    float w = Y[q][i] * (float)Fh[q][i];
                    V[q][i] = mt ? w : V[q][i];
                }
        }
    } else {
#pragma unroll
        for (int s = CLT - 1; s >= 0; --s) {
            half4_t Fh[4];
#pragma unroll
            for (int kc = 0; kc < 4; ++kc)
                Fh[kc] = *(const half4_t*)(Fbase + s * SSLAB + kc * 32);
            half4_t Xh[4];
#pragma unroll
            for (int kc = 0; kc < 4; ++kc)
                Xh[kc] = pack4(V[kc][0] * (float)Fh[kc][0],
                               V[kc][1] * (float)Fh[kc][1],
                               V[kc][2] * (float)Fh[kc][2],
                               V[kc][3] * (float)Fh[kc][3]);
            f32x4_t Y[4];
#pragma unroll
            for (int q = 0; q < 4; ++q) {
                f32x4_t a0 = {0.0f, 0.0f, 0.0f, 0.0f};
                f32x4_t a1 = {0.0f, 0.0f, 0.0f, 0.0f};
                a0 = __builtin_amdgcn_mfma_f32_16x16x16f16(A[q][0], Xh[0], a0, 0, 0, 0);
                a0 = __builtin_amdgcn_mfma_f32_16x16x16f16(A[q][1], Xh[1], a0, 0, 0, 0);
                a1 = __builtin_amdgcn_mfma_f32_16x16x16f16(A[q][2], Xh[2], a1, 0, 0, 0);
                a1 = __builtin_amdgcn_mfma_f32_16x16x16f16(A[q][3], Xh[3], a1, 0, 0, 0);
                Y[q] = a0 + a1;
            }
            int mt = (mbits >> s) & 1;
#pragma unroll
            for (int q = 0; q < 4; ++q)
#pragma unroll
                for (int i = 0; i < 4; ++i)
                    V[q][i] = mt ? Y[q][i] : V[q][i];
        }
    }

    // ---- epilogue: transposed junction reduction ----
    __syncthreads();                       // all Flds (staging) reads done
    float* Rarr = (float*)Flds;            // [16][RWS]
    float* Warr = Rarr + 16 * RWS;
    {
        float* dst = (fwd ? Rarr : Warr) + rlo * RWS + 4 * h;
#pragma unroll
        for (int q = 0; q < 4; ++q) *(f32x4_t*)(dst + 16 * q) = V[q];
    }
    __syncthreads();

    if (fwd) {
        // quad per junction: c = lane>>2 in [0,15], sub = lane&3 covers 16 elems
        const int c   = lane >> 2;
        const int sub = lane & 3;
        float dot = 0.0f, rho = 0.0f;
        {
            const float* br = Rarr + (c == 0 ? 0 : (c - 1)) * RWS + sub * 16;
            const float* bw = Warr + c * RWS + sub * 16;
#pragma unroll
            for (int u = 0; u < 4; ++u) {
                f32x4_t rv = *(const f32x4_t*)(br + 4 * u);
                f32x4_t wv = *(const f32x4_t*)(bw + 4 * u);
#pragma unroll
                for (int i = 0; i < 4; ++i) {
                    dot = fmaf(rv[i], wv[i], dot);
                    rho += wv[i];
                }
            }
        }
        dot += dpp_xor1(dot); dot += dpp_xor2(dot);
        rho += dpp_xor1(rho); rho += dpp_xor2(rho);

        float part = 0.0f;
        if (c >= 1 && sub == 0) part = __logf(dot) - __logf(rho);
        if (h == 0) part += C;             // per-run Cf (16 runs at lanes 0..15)
        float tot = wave_red_sum(part);
        if (lane == 0) Jpart[b * NG + g] = tot;

        if (rlo == 15) {
            float* dst = rB + ((size_t)b * NG + g) * 64 + 4 * h;
#pragma unroll
            for (int q = 0; q < 4; ++q) *(f32x4_t*)(dst + 16 * q) = V[q];
        }
    } else {
        if (rlo == 0) {
            float* dst = wB + ((size_t)b * NG + g) * 64 + 4 * h;
#pragma unroll
            for (int q = 0; q < 4; ++q) *(f32x4_t*)(dst + 16 * q) = V[q];
        }
    }
}

// ---------------------------------------------------------------------------
// Glue (fused final): per batch, transposed boundary junctions + end-term +
// Jpart sum -> diff[b] = numtrans[b] - den[b]. Last-finished block (int
// atomic counter) sums all 256 diffs in fixed order -> out[0]. Deterministic.
// ---------------------------------------------------------------------------
__global__ __launch_bounds__(64) void crf_glue_kernel(
    const float* __restrict__ rB,
    const float* __restrict__ wB,
    const float* __restrict__ Jpart,
    const float* __restrict__ endT,
    const float* __restrict__ numtrans,
    float* __restrict__ diffs,   // [BSZ]
    int*   __restrict__ counter, // zeroed by memsetAsync each call
    float* __restrict__ out)
{
    const int b    = blockIdx.x;
    const int lane = threadIdx.x;
    const int c    = lane >> 2;    // quad id: 0 = end-term, 1..15 = junctions
    const int sub  = lane & 3;

    float dot = 0.0f, rho = 0.0f;
    if (c == 0) {
        // end-term: fin = sum_j rB[NG-1][j] * exp(endT[j])
        const float* br = rB + ((size_t)b * NG + NG - 1) * 64 + sub * 16;
#pragma unroll
        for (int u = 0; u < 4; ++u) {
            f32x4_t rv = *(const f32x4_t*)(br + 4 * u);
            f32x4_t ev = *(const f32x4_t*)(endT + sub * 16 + 4 * u);
#pragma unroll
            for (int i = 0; i < 4; ++i) dot = fmaf(rv[i], __expf(ev[i]), dot);
        }
    } else {
        const float* br = rB + ((size_t)b * NG + c - 1) * 64 + sub * 16;
        const float* bw = wB + ((size_t)b * NG + c) * 64 + sub * 16;
#pragma unroll
        for (int u = 0; u < 4; ++u) {
            f32x4_t rv = *(const f32x4_t*)(br + 4 * u);
            f32x4_t wv = *(const f32x4_t*)(bw + 4 * u);
#pragma unroll
            for (int i = 0; i < 4; ++i) {
                dot = fmaf(rv[i], wv[i], dot);
                rho += wv[i];
            }
        }
    }
    dot += dpp_xor1(dot); dot += dpp_xor2(dot);
    rho += dpp_xor1(rho); rho += dpp_xor2(rho);

    float part = 0.0f;
    if (sub == 0) {
        part = (c == 0) ? __logf(dot) : (__logf(dot) - __logf(rho));
    }
    float contrib = part + ((lane < NG) ? Jpart[b * NG + lane] : 0.0f);
    float den = wave_red_sum(contrib);

    __shared__ int slast;
    if (lane == 0) {
        diffs[b] = numtrans[b] - den;
        __threadfence();
        int old = atomicAdd(counter, 1);
        slast = (old == BSZ - 1) ? 1 : 0;
    }
    __syncthreads();
    if (slast) {
        __threadfence();   // acquire: other blocks' diffs visible
        float x = diffs[lane] + diffs[lane + 64] +
                  diffs[lane + 128] + diffs[lane + 192];
        float tot = wave_red_sum(x);
        if (lane == 0) out[0] = tot;
    }
}

// ---------------------------------------------------------------------------
extern "C" void kernel_launch(void* const* d_in, const int* in_sizes, int n_in,
                              void* d_out, int out_size, void* d_ws, size_t ws_size,
                              hipStream_t stream)
{
    const float* logits = (const float*)d_in[0];
    const int*   tags   = (const int*)  d_in[1];
    const int*   mask   = (const int*)  d_in[2];
    const float* trans  = (const float*)d_in[3];
    const float* startT = (const float*)d_in[4];
    const float* endT   = (const float*)d_in[5];
    float* out = (float*)d_out;
    float* ws  = (float*)d_ws;

    float* numtrans = ws;                                  // BSZ
    float* diffs    = ws + BSZ;                            // BSZ
    float* Jpart    = ws + 2 * BSZ;                        // BSZ*NG
    float* rB       = Jpart + (size_t)BSZ * NG;            // BSZ*NG*64
    float* wB       = rB + (size_t)BSZ * NG * 64;          // BSZ*NG*64
    int*   counter  = (int*)(wB + (size_t)BSZ * NG * 64);  // 1

    hipMemsetAsync(counter, 0, sizeof(int), stream);
    crf_fat_kernel<<<BSZ + BSZ * NG, 128, 0, stream>>>(
        logits, tags, mask, trans, startT, endT, rB, wB, Jpart, numtrans);
    crf_glue_kernel<<<BSZ, 64, 0, stream>>>(rB, wB, Jpart, endT, numtrans,
                                            diffs, counter, out);
}

// Round 17
// 57.838 us; speedup vs baseline: 1.2328x; 1.2328x over previous
//
#include <hip/hip_runtime.h>

#define BSZ 256
#define SEQ 2048
#define NT  64
#define KS  5.0f

#define CLT 8                     // steps per chunk
#define SC  (16 * CLT)            // steps per superchunk = 128
#define NG  (SEQ / SC)            // superchunks per sequence = 16

#define SROW  136                 // LDS bytes per (s,k) row: 64 f16 + 8 pad
#define SSLAB (16 * SROW + 8)     // LDS bytes per s-slab (16 runs) + pad
#define RWS   68                  // r/w LDS row stride in floats

typedef __fp16 half2_t __attribute__((ext_vector_type(2)));
typedef __fp16 half4_t __attribute__((ext_vector_type(4)));
typedef float  f32x4_t __attribute__((ext_vector_type(4)));
typedef int    int2_t  __attribute__((ext_vector_type(2)));

static __device__ __forceinline__ float wave_red_sum(float x) {
#pragma unroll
    for (int d = 1; d < 64; d <<= 1) x += __shfl_xor(x, d);
    return x;
}

// intra-quad xor-1 / xor-2 via DPP quad_perm (pure VALU, no LDS pipe)
static __device__ __forceinline__ float dpp_xor1(float v) {
    return __builtin_bit_cast(float,
        __builtin_amdgcn_update_dpp(0, __builtin_bit_cast(int, v), 0xB1, 0xF, 0xF, true));
}
static __device__ __forceinline__ float dpp_xor2(float v) {
    return __builtin_bit_cast(float,
        __builtin_amdgcn_update_dpp(0, __builtin_bit_cast(int, v), 0x4E, 0xF, 0xF, true));
}

static __device__ __forceinline__ half4_t pack4(float a, float b, float c, float d) {
    half2_t lo = __builtin_amdgcn_cvt_pkrtz(a, b);
    half2_t hi = __builtin_amdgcn_cvt_pkrtz(c, d);
    int2_t t;
    t.x = __builtin_bit_cast(int, lo);
    t.y = __builtin_bit_cast(int, hi);
    return __builtin_bit_cast(half4_t, t);
}

// ---------------------------------------------------------------------------
// Pre-kernel: f16 A-fragment tables. EtabF = E^T (fwd), EtabB = E (bwd).
// Entry [slot*64+lane], slot=q*4+kc, lane=(h<<4)|rlo; elem i: k=16kc+4h+i,
// m=16q+rlo.
// ---------------------------------------------------------------------------
__global__ __launch_bounds__(128) void crf_pre_kernel(
    const float* __restrict__ trans,
    half4_t* __restrict__ EtabF,
    half4_t* __restrict__ EtabB)
{
    for (int e = threadIdx.x; e < 1024; e += 128) {
        int lane = e & 63, slot = e >> 6;
        int q = slot >> 2, kc = slot & 3;
        int rlo = lane & 15, h = lane >> 4;
        int m = 16 * q + rlo;
        float f[4], bb[4];
#pragma unroll
        for (int i = 0; i < 4; ++i) {
            int k = 16 * kc + 4 * h + i;
            f[i]  = __expf(trans[k * NT + m]);
            bb[i] = __expf(trans[m * NT + k]);
        }
        EtabF[e] = pack4(f[0], f[1], f[2], f[3]);
        EtabB[e] = pack4(bb[0], bb[1], bb[2], bb[3]);
    }
}

// ---------------------------------------------------------------------------
// Fat kernel. Blocks [0,BSZ): numerator. Blocks [BSZ,...): pass1 per
// (batch, superchunk): stage F->LDS coalesced; A-fragments from table;
// wave0 16 fwd runs, wave1 16 bwd runs (MFMA chains, no renorm — f32 range
// suffices, Cf = KS*popcount); epilogue: transposed junction reduction
// (quad per junction, DPP), fwd wave only; boundary r/w vectors to global.
// ---------------------------------------------------------------------------
__global__ __launch_bounds__(128) void crf_fat_kernel(
    const float* __restrict__ logits,
    const int*   __restrict__ tags,
    const int*   __restrict__ mask,
    const float* __restrict__ trans,
    const float* __restrict__ startT,
    const float* __restrict__ endT,
    const half4_t* __restrict__ EtabF,
    const half4_t* __restrict__ EtabB,
    float* __restrict__ rB,      // [BSZ][NG][64]
    float* __restrict__ wB,      // [BSZ][NG][64]
    float* __restrict__ Jpart,   // [BSZ][NG]
    float* __restrict__ numtrans)
{
    __shared__ __align__(16) unsigned char Flds[CLT * SSLAB];
    __shared__ int lmbits[16];

    if (blockIdx.x < BSZ) {
        // ---------------- numerator branch ----------------
        const int b   = blockIdx.x;
        const int tid = threadIdx.x;
        float* redf = (float*)Flds;
        int*   redi = (int*)(Flds + 512);

        const int*   __restrict__ tg = tags + (size_t)b * SEQ;
        const int*   __restrict__ mk = mask + (size_t)b * SEQ;
        const float* __restrict__ Lr = logits + (size_t)b * SEQ * NT;

        float acc = 0.0f;
        int   cnt = 0;
        for (int t = tid; t < SEQ; t += 128) {
            int mt  = mk[t];
            cnt += mt;
            int tgt = tg[t] * mt;
            if (t < SEQ - 1) {
                int m1 = mk[t + 1];
                acc += trans[tgt * NT + tg[t + 1] * m1] * (float)m1;
                acc += Lr[t * NT + tgt] * (float)mt;
            }
        }
        redf[tid] = acc;
        redi[tid] = cnt;
        __syncthreads();
        for (int off = 64; off > 0; off >>= 1) {
            if (tid < off) {
                redf[tid] += redf[tid + off];
                redi[tid] += redi[tid + off];
            }
            __syncthreads();
        }
        if (tid == 0) {
            int   last_idx = redi[0] - 1;
            int   m_last   = mk[SEQ - 1];
            int   tag0     = tg[0] * mk[0];
            int   last_tag = tg[last_idx] * mk[last_idx];
            float r = redf[0] + startT[tag0] + endT[last_tag];
            r += Lr[(size_t)(SEQ - 1) * NT + last_tag] * (float)m_last;
            numtrans[b] = r;
        }
        return;
    }

    // ---------------- pass1 branch ----------------
    const int blk  = blockIdx.x - BSZ;
    const int b    = blk / NG;
    const int g    = blk % NG;
    const int tid  = threadIdx.x;
    const bool fwd = (tid >> 6) == 0;
    const int lane = tid & 63;
    const int rlo  = lane & 15;     // run (sub-chunk) index
    const int h    = lane >> 4;

    // ---- stage F (f16) into LDS, coalesced, loads batched 8-deep ----
    const float* __restrict__ Lg = logits + ((size_t)b * SEQ + (size_t)g * SC) * NT;
#pragma unroll
    for (int hh = 0; hh < 2; ++hh) {
        f32x4_t xb[8];
#pragma unroll
        for (int jj = 0; jj < 8; ++jj) {
            int gci = (hh * 8 + jj) * 128 + tid;
            xb[jj] = *(const f32x4_t*)(Lg + (size_t)(gci >> 4) * NT + (gci & 15) * 4);
        }
#pragma unroll
        for (int jj = 0; jj < 8; ++jj) {
            int gci = (hh * 8 + jj) * 128 + tid;
            int row = gci >> 4;
            int col = gci & 15;
            int k   = row / CLT;
            int s   = row % CLT;
            half2_t p0 = __builtin_amdgcn_cvt_pkrtz(__expf(xb[jj][0] - KS), __expf(xb[jj][1] - KS));
            half2_t p1 = __builtin_amdgcn_cvt_pkrtz(__expf(xb[jj][2] - KS), __expf(xb[jj][3] - KS));
            int2_t w;
            w.x = __builtin_bit_cast(int, p0);
            w.y = __builtin_bit_cast(int, p1);
            *(int2_t*)(Flds + s * SSLAB + k * SROW + col * 8) = w;
        }
    }
    if (tid < 16) {
        const int* mk = mask + (size_t)b * SEQ + (size_t)g * SC + tid * CLT;
        int bits = 0;
#pragma unroll
        for (int s = 0; s < CLT; ++s) bits |= (mk[s] ? 1 : 0) << s;
        if (g == 0 && tid == 0) bits &= ~1;   // t=0 is the init, not a D-step
        lmbits[tid] = bits;
    }

    // ---- A fragments from table (coalesced L2 loads) ----
    const half4_t* __restrict__ Et = fwd ? EtabF : EtabB;
    half4_t A[4][4];
#pragma unroll
    for (int q = 0; q < 4; ++q)
#pragma unroll
        for (int kc = 0; kc < 4; ++kc)
            A[q][kc] = Et[(q * 4 + kc) * 64 + lane];

    __syncthreads();

    const int mbits = lmbits[rlo];
    f32x4_t V[4];
    float C = KS * (float)__builtin_popcount(mbits);   // Cf, no renorm needed
#pragma unroll
    for (int q = 0; q < 4; ++q)
#pragma unroll
        for (int i = 0; i < 4; ++i) V[q][i] = 1.0f;

    if (fwd && g == 0 && rlo == 0) {
        // true init for global chunk 0: alpha0 = start + em(t=0)
        float mx = -1e30f;
        f32x4_t al[4];
#pragma unroll
        for (int q = 0; q < 4; ++q) {
            f32x4_t em = *(const f32x4_t*)(logits + (size_t)b * SEQ * NT + 16 * q + 4 * h);
            f32x4_t st = *(const f32x4_t*)(startT + 16 * q + 4 * h);
#pragma unroll
            for (int i = 0; i < 4; ++i) {
                al[q][i] = st[i] + em[i];
                mx = fmaxf(mx, al[q][i]);
            }
        }
        mx = fmaxf(mx, __shfl_xor(mx, 16));
        mx = fmaxf(mx, __shfl_xor(mx, 32));
        C += mx;
#pragma unroll
        for (int q = 0; q < 4; ++q)
#pragma unroll
            for (int i = 0; i < 4; ++i) V[q][i] = __expf(al[q][i] - mx);
    }

    const unsigned char* Fbase = Flds + rlo * SROW + h * 8;

    if (fwd) {
#pragma unroll
        for (int s = 0; s < CLT; ++s) {
            half4_t Fh[4];
#pragma unroll
            for (int q = 0; q < 4; ++q)
                Fh[q] = *(const half4_t*)(Fbase + s * SSLAB + q * 32);
            half4_t Xh[4];
#pragma unroll
            for (int kc = 0; kc < 4; ++kc)
                Xh[kc] = pack4(V[kc][0], V[kc][1], V[kc][2], V[kc][3]);
            f32x4_t Y[4];
#pragma unroll
            for (int q = 0; q < 4; ++q) {
                f32x4_t a0 = {0.0f, 0.0f, 0.0f, 0.0f};
                f32x4_t a1 = {0.0f, 0.0f, 0.0f, 0.0f};
                a0 = __builtin_amdgcn_mfma_f32_16x16x16f16(A[q][0], Xh[0], a0, 0, 0, 0);
                a0 = __builtin_amdgcn_mfma_f32_16x16x16f16(A[q][1], Xh[1], a0, 0, 0, 0);
                a1 = __builtin_amdgcn_mfma_f32_16x16x16f16(A[q][2], Xh[2], a1, 0, 0, 0);
                a1 = __builtin_amdgcn_mfma_f32_16x16x16f16(A[q][3], Xh[3], a1, 0, 0, 0);
                Y[q] = a0 + a1;
            }
            int mt = (mbits >> s) & 1;
#pragma unroll
            for (int q = 0; q < 4; ++q)
#pragma unroll
                for (int i = 0; i < 4; ++i) {
                    float w = Y[q][i] * (float)Fh[q][i];
                    V[q][i] = mt ? w : V[q][i];
                }
        }
    } else {
#pragma unroll
        for (int s = CLT - 1; s >= 0; --s) {
            half4_t Fh[4];
#pragma unroll
            for (int kc = 0; kc < 4; ++kc)
                Fh[kc] = *(const half4_t*)(Fbase + s * SSLAB + kc * 32);
            half4_t Xh[4];
#pragma unroll
            for (int kc = 0; kc < 4; ++kc)
                Xh[kc] = pack4(V[kc][0] * (float)Fh[kc][0],
                               V[kc][1] * (float)Fh[kc][1],
                               V[kc][2] * (float)Fh[kc][2],
                               V[kc][3] * (float)Fh[kc][3]);
            f32x4_t Y[4];
#pragma unroll
            for (int q = 0; q < 4; ++q) {
                f32x4_t a0 = {0.0f, 0.0f, 0.0f, 0.0f};
                f32x4_t a1 = {0.0f, 0.0f, 0.0f, 0.0f};
                a0 = __builtin_amdgcn_mfma_f32_16x16x16f16(A[q][0], Xh[0], a0, 0, 0, 0);
                a0 = __builtin_amdgcn_mfma_f32_16x16x16f16(A[q][1], Xh[1], a0, 0, 0, 0);
                a1 = __builtin_amdgcn_mfma_f32_16x16x16f16(A[q][2], Xh[2], a1, 0, 0, 0);
                a1 = __builtin_amdgcn_mfma_f32_16x16x16f16(A[q][3], Xh[3], a1, 0, 0, 0);
                Y[q] = a0 + a1;
            }
            int mt = (mbits >> s) & 1;
#pragma unroll
            for (int q = 0; q < 4; ++q)
#pragma unroll
                for (int i = 0; i < 4; ++i)
                    V[q][i] = mt ? Y[q][i] : V[q][i];
        }
    }

    // ---- epilogue: transposed junction reduction ----
    __syncthreads();                       // all Flds (staging) reads done
    float* Rarr = (float*)Flds;            // [16][RWS]
    float* Warr = Rarr + 16 * RWS;
    {
        float* dst = (fwd ? Rarr : Warr) + rlo * RWS + 4 * h;
#pragma unroll
        for (int q = 0; q < 4; ++q) *(f32x4_t*)(dst + 16 * q) = V[q];
    }
    __syncthreads();

    if (fwd) {
        // quad per junction: c = lane>>2 in [0,15], sub = lane&3 covers 16 elems
        const int c   = lane >> 2;
        const int sub = lane & 3;
        float dot = 0.0f, rho = 0.0f;
        {
            const float* br = Rarr + (c == 0 ? 0 : (c - 1)) * RWS + sub * 16;
            const float* bw = Warr + c * RWS + sub * 16;
#pragma unroll
            for (int u = 0; u < 4; ++u) {
                f32x4_t rv = *(const f32x4_t*)(br + 4 * u);
                f32x4_t wv = *(const f32x4_t*)(bw + 4 * u);
#pragma unroll
                for (int i = 0; i < 4; ++i) {
                    dot = fmaf(rv[i], wv[i], dot);
                    rho += wv[i];
                }
            }
        }
        dot += dpp_xor1(dot); dot += dpp_xor2(dot);
        rho += dpp_xor1(rho); rho += dpp_xor2(rho);

        float part = 0.0f;
        if (c >= 1 && sub == 0) part = __logf(dot) - __logf(rho);
        if (h == 0) part += C;             // per-run Cf (16 runs at lanes 0..15)
        float tot = wave_red_sum(part);
        if (lane == 0) Jpart[b * NG + g] = tot;

        if (rlo == 15) {
            float* dst = rB + ((size_t)b * NG + g) * 64 + 4 * h;
#pragma unroll
            for (int q = 0; q < 4; ++q) *(f32x4_t*)(dst + 16 * q) = V[q];
        }
    } else {
        if (rlo == 0) {
            float* dst = wB + ((size_t)b * NG + g) * 64 + 4 * h;
#pragma unroll
            for (int q = 0; q < 4; ++q) *(f32x4_t*)(dst + 16 * q) = V[q];
        }
    }
}

// ---------------------------------------------------------------------------
// Glue (fused final): per batch, transposed boundary junctions + end-term +
// Jpart sum -> diff[b] = numtrans[b] - den[b]. Last-finished block (int
// atomic counter) sums all 256 diffs in fixed order -> out[0]. Deterministic.
// ---------------------------------------------------------------------------
__global__ __launch_bounds__(64) void crf_glue_kernel(
    const float* __restrict__ rB,
    const float* __restrict__ wB,
    const float* __restrict__ Jpart,
    const float* __restrict__ endT,
    const float* __restrict__ numtrans,
    float* __restrict__ diffs,   // [BSZ]
    int*   __restrict__ counter, // zeroed by memsetAsync each call
    float* __restrict__ out)
{
    const int b    = blockIdx.x;
    const int lane = threadIdx.x;
    const int c    = lane >> 2;    // quad id: 0 = end-term, 1..15 = junctions
    const int sub  = lane & 3;

    float dot = 0.0f, rho = 0.0f;
    if (c == 0) {
        // end-term: fin = sum_j rB[NG-1][j] * exp(endT[j])
        const float* br = rB + ((size_t)b * NG + NG - 1) * 64 + sub * 16;
#pragma unroll
        for (int u = 0; u < 4; ++u) {
            f32x4_t rv = *(const f32x4_t*)(br + 4 * u);
            f32x4_t ev = *(const f32x4_t*)(endT + sub * 16 + 4 * u);
#pragma unroll
            for (int i = 0; i < 4; ++i) dot = fmaf(rv[i], __expf(ev[i]), dot);
        }
    } else {
        const float* br = rB + ((size_t)b * NG + c - 1) * 64 + sub * 16;
        const float* bw = wB + ((size_t)b * NG + c) * 64 + sub * 16;
#pragma unroll
        for (int u = 0; u < 4; ++u) {
            f32x4_t rv = *(const f32x4_t*)(br + 4 * u);
            f32x4_t wv = *(const f32x4_t*)(bw + 4 * u);
#pragma unroll
            for (int i = 0; i < 4; ++i) {
                dot = fmaf(rv[i], wv[i], dot);
                rho += wv[i];
            }
        }
    }
    dot += dpp_xor1(dot); dot += dpp_xor2(dot);
    rho += dpp_xor1(rho); rho += dpp_xor2(rho);

    float part = 0.0f;
    if (sub == 0) {
        part = (c == 0) ? __logf(dot) : (__logf(dot) - __logf(rho));
    }
    float contrib = part + ((lane < NG) ? Jpart[b * NG + lane] : 0.0f);
    float den = wave_red_sum(contrib);

    __shared__ int slast;
    if (lane == 0) {
        diffs[b] = numtrans[b] - den;
        __threadfence();
        int old = atomicAdd(counter, 1);
        slast = (old == BSZ - 1) ? 1 : 0;
    }
    __syncthreads();
    if (slast) {
        __threadfence();   // acquire: other blocks' diffs visible
        float x = diffs[lane] + diffs[lane + 64] +
                  diffs[lane + 128] + diffs[lane + 192];
        float tot = wave_red_sum(x);
        if (lane == 0) out[0] = tot;
    }
}

// ---------------------------------------------------------------------------
extern "C" void kernel_launch(void* const* d_in, const int* in_sizes, int n_in,
                              void* d_out, int out_size, void* d_ws, size_t ws_size,
                              hipStream_t stream)
{
    const float* logits = (const float*)d_in[0];
    const int*   tags   = (const int*)  d_in[1];
    const int*   mask   = (const int*)  d_in[2];
    const float* trans  = (const float*)d_in[3];
    const float* startT = (const float*)d_in[4];
    const float* endT   = (const float*)d_in[5];
    float* out = (float*)d_out;
    float* ws  = (float*)d_ws;

    float*   numtrans = ws;                                  // BSZ
    float*   diffs    = ws + BSZ;                            // BSZ
    float*   Jpart    = ws + 2 * BSZ;                        // BSZ*NG
    float*   rB       = Jpart + (size_t)BSZ * NG;            // BSZ*NG*64
    float*   wB       = rB + (size_t)BSZ * NG * 64;          // BSZ*NG*64
    half4_t* EtabF    = (half4_t*)(wB + (size_t)BSZ * NG * 64);  // 1024 half4
    half4_t* EtabB    = EtabF + 1024;                        // 1024 half4
    int*     counter  = (int*)(EtabB + 1024);                // 1

    hipMemsetAsync(counter, 0, sizeof(int), stream);
    crf_pre_kernel<<<1, 128, 0, stream>>>(trans, EtabF, EtabB);
    crf_fat_kernel<<<BSZ + BSZ * NG, 128, 0, stream>>>(
        logits, tags, mask, trans, startT, endT, EtabF, EtabB, rB, wB, Jpart, numtrans);
    crf_glue_kernel<<<BSZ, 64, 0, stream>>>(rB, wB, Jpart, endT, numtrans,
                                            diffs, counter, out);
}

// Round 18
// 57.551 us; speedup vs baseline: 1.2390x; 1.0050x over previous
//
#include <hip/hip_runtime.h>

#define BSZ 256
#define SEQ 2048
#define NT  64
#define KS  5.0f

#define CLT 8                     // steps per chunk
#define SC  (16 * CLT)            // steps per superchunk = 128
#define NG  (SEQ / SC)            // superchunks per sequence = 16
#define NP  (NG / 2)              // superchunk pairs per sequence = 8

#define SROW  136                 // LDS bytes per (s,k) row: 64 f16 + 8 pad
#define SSLAB (16 * SROW + 8)     // LDS bytes per s-slab (16 runs) + pad
#define FBYTES (CLT * SSLAB)      // bytes per superchunk F-buffer
#define RWS   68                  // r/w LDS row stride in floats

typedef __fp16 half2_t __attribute__((ext_vector_type(2)));
typedef __fp16 half4_t __attribute__((ext_vector_type(4)));
typedef float  f32x4_t __attribute__((ext_vector_type(4)));
typedef int    int2_t  __attribute__((ext_vector_type(2)));

static __device__ __forceinline__ float wave_red_sum(float x) {
#pragma unroll
    for (int d = 1; d < 64; d <<= 1) x += __shfl_xor(x, d);
    return x;
}

// intra-quad xor-1 / xor-2 via DPP quad_perm (pure VALU, no LDS pipe)
static __device__ __forceinline__ float dpp_xor1(float v) {
    return __builtin_bit_cast(float,
        __builtin_amdgcn_update_dpp(0, __builtin_bit_cast(int, v), 0xB1, 0xF, 0xF, true));
}
static __device__ __forceinline__ float dpp_xor2(float v) {
    return __builtin_bit_cast(float,
        __builtin_amdgcn_update_dpp(0, __builtin_bit_cast(int, v), 0x4E, 0xF, 0xF, true));
}

static __device__ __forceinline__ half4_t pack4(float a, float b, float c, float d) {
    half2_t lo = __builtin_amdgcn_cvt_pkrtz(a, b);
    half2_t hi = __builtin_amdgcn_cvt_pkrtz(c, d);
    int2_t t;
    t.x = __builtin_bit_cast(int, lo);
    t.y = __builtin_bit_cast(int, hi);
    return __builtin_bit_cast(half4_t, t);
}

// ---------------------------------------------------------------------------
// Pre-kernel: f16 A-fragment tables. EtabF = E^T (fwd), EtabB = E (bwd).
// Entry [slot*64+lane], slot=q*4+kc, lane=(h<<4)|rlo; elem i: k=16kc+4h+i,
// m=16q+rlo.
// ---------------------------------------------------------------------------
__global__ __launch_bounds__(128) void crf_pre_kernel(
    const float* __restrict__ trans,
    half4_t* __restrict__ EtabF,
    half4_t* __restrict__ EtabB)
{
    for (int e = threadIdx.x; e < 1024; e += 128) {
        int lane = e & 63, slot = e >> 6;
        int q = slot >> 2, kc = slot & 3;
        int rlo = lane & 15, h = lane >> 4;
        int m = 16 * q + rlo;
        float f[4], bb[4];
#pragma unroll
        for (int i = 0; i < 4; ++i) {
            int k = 16 * kc + 4 * h + i;
            f[i]  = __expf(trans[k * NT + m]);
            bb[i] = __expf(trans[m * NT + k]);
        }
        EtabF[e] = pack4(f[0], f[1], f[2], f[3]);
        EtabB[e] = pack4(bb[0], bb[1], bb[2], bb[3]);
    }
}

// ---------------------------------------------------------------------------
// Fat kernel (256 threads). Blocks [0,BSZ): numerator. Blocks [BSZ,...):
// pass1 per (batch, superchunk PAIR): stage a contiguous 64KB logits window
// (2 superchunks) coalesced -> F f16 into two LDS buffers; 4 waves:
// w0/w1 = fwd/bwd of g=2p, w2/w3 = fwd/bwd of 2p+1. MFMA chains, no renorm
// (Cf = KS*popcount); transposed DPP junction epilogue per fwd wave;
// boundary r/w vectors to global.
// ---------------------------------------------------------------------------
__global__ __launch_bounds__(256) void crf_fat_kernel(
    const float* __restrict__ logits,
    const int*   __restrict__ tags,
    const int*   __restrict__ mask,
    const float* __restrict__ trans,
    const float* __restrict__ startT,
    const float* __restrict__ endT,
    const half4_t* __restrict__ EtabF,
    const half4_t* __restrict__ EtabB,
    float* __restrict__ rB,      // [BSZ][NG][64]
    float* __restrict__ wB,      // [BSZ][NG][64]
    float* __restrict__ Jpart,   // [BSZ][NG]
    float* __restrict__ numtrans)
{
    __shared__ __align__(16) unsigned char Flds[2 * FBYTES];
    __shared__ int lmbits[32];

    if (blockIdx.x < BSZ) {
        // ---------------- numerator branch ----------------
        const int b   = blockIdx.x;
        const int tid = threadIdx.x;
        float* redf = (float*)Flds;
        int*   redi = (int*)(Flds + 1024);

        const int*   __restrict__ tg = tags + (size_t)b * SEQ;
        const int*   __restrict__ mk = mask + (size_t)b * SEQ;
        const float* __restrict__ Lr = logits + (size_t)b * SEQ * NT;

        float acc = 0.0f;
        int   cnt = 0;
        for (int t = tid; t < SEQ; t += 256) {
            int mt  = mk[t];
            cnt += mt;
            int tgt = tg[t] * mt;
            if (t < SEQ - 1) {
                int m1 = mk[t + 1];
                acc += trans[tgt * NT + tg[t + 1] * m1] * (float)m1;
                acc += Lr[t * NT + tgt] * (float)mt;
            }
        }
        redf[tid] = acc;
        redi[tid] = cnt;
        __syncthreads();
        for (int off = 128; off > 0; off >>= 1) {
            if (tid < off) {
                redf[tid] += redf[tid + off];
                redi[tid] += redi[tid + off];
            }
            __syncthreads();
        }
        if (tid == 0) {
            int   last_idx = redi[0] - 1;
            int   m_last   = mk[SEQ - 1];
            int   tag0     = tg[0] * mk[0];
            int   last_tag = tg[last_idx] * mk[last_idx];
            float r = redf[0] + startT[tag0] + endT[last_tag];
            r += Lr[(size_t)(SEQ - 1) * NT + last_tag] * (float)m_last;
            numtrans[b] = r;
        }
        return;
    }

    // ---------------- pass1 branch ----------------
    const int blk  = blockIdx.x - BSZ;
    const int b    = blk / NP;
    const int p    = blk % NP;
    const int tid  = threadIdx.x;
    const int wave = tid >> 6;
    const int lane = tid & 63;
    const int half = wave >> 1;          // which superchunk of the pair
    const bool fwd = (wave & 1) == 0;
    const int g    = 2 * p + half;
    const int rlo  = lane & 15;          // run (sub-chunk) index within superchunk
    const int h    = lane >> 4;

    // ---- stage F (f16) into LDS: contiguous 64KB window, coalesced ----
    const float* __restrict__ Lg = logits + ((size_t)b * SEQ + (size_t)(2 * p) * SC) * NT;
#pragma unroll
    for (int hh = 0; hh < 2; ++hh) {
        f32x4_t xb[8];
#pragma unroll
        for (int jj = 0; jj < 8; ++jj) {
            int gci = (hh * 8 + jj) * 256 + tid;
            xb[jj] = *(const f32x4_t*)(Lg + (size_t)(gci >> 4) * NT + (gci & 15) * 4);
        }
#pragma unroll
        for (int jj = 0; jj < 8; ++jj) {
            int gci  = (hh * 8 + jj) * 256 + tid;
            int row  = gci >> 4;             // 0..255 within the pair window
            int col  = gci & 15;
            int buf  = row >> 7;
            int lrow = row & 127;
            int k    = lrow / CLT;
            int s    = lrow % CLT;
            half2_t p0 = __builtin_amdgcn_cvt_pkrtz(__expf(xb[jj][0] - KS), __expf(xb[jj][1] - KS));
            half2_t p1 = __builtin_amdgcn_cvt_pkrtz(__expf(xb[jj][2] - KS), __expf(xb[jj][3] - KS));
            int2_t w;
            w.x = __builtin_bit_cast(int, p0);
            w.y = __builtin_bit_cast(int, p1);
            *(int2_t*)(Flds + buf * FBYTES + s * SSLAB + k * SROW + col * 8) = w;
        }
    }
    if (tid < 32) {
        // run tid covers rows [tid*CLT, tid*CLT+CLT) of the 256-row window
        const int* mk = mask + (size_t)b * SEQ + (size_t)(2 * p) * SC + tid * CLT;
        int bits = 0;
#pragma unroll
        for (int s = 0; s < CLT; ++s) bits |= (mk[s] ? 1 : 0) << s;
        if (p == 0 && tid == 0) bits &= ~1;   // t=0 is the init, not a D-step
        lmbits[tid] = bits;
    }

    // ---- A fragments from table (coalesced L2 loads) ----
    const half4_t* __restrict__ Et = fwd ? EtabF : EtabB;
    half4_t A[4][4];
#pragma unroll
    for (int q = 0; q < 4; ++q)
#pragma unroll
        for (int kc = 0; kc < 4; ++kc)
            A[q][kc] = Et[(q * 4 + kc) * 64 + lane];

    __syncthreads();

    const int mbits = lmbits[half * 16 + rlo];
    f32x4_t V[4];
    float C = KS * (float)__builtin_popcount(mbits);   // Cf, no renorm needed
#pragma unroll
    for (int q = 0; q < 4; ++q)
#pragma unroll
        for (int i = 0; i < 4; ++i) V[q][i] = 1.0f;

    if (fwd && g == 0 && rlo == 0) {
        // true init for global chunk 0: alpha0 = start + em(t=0)
        float mx = -1e30f;
        f32x4_t al[4];
#pragma unroll
        for (int q = 0; q < 4; ++q) {
            f32x4_t em = *(const f32x4_t*)(logits + (size_t)b * SEQ * NT + 16 * q + 4 * h);
            f32x4_t st = *(const f32x4_t*)(startT + 16 * q + 4 * h);
#pragma unroll
            for (int i = 0; i < 4; ++i) {
                al[q][i] = st[i] + em[i];
                mx = fmaxf(mx, al[q][i]);
            }
        }
        mx = fmaxf(mx, __shfl_xor(mx, 16));
        mx = fmaxf(mx, __shfl_xor(mx, 32));
        C += mx;
#pragma unroll
        for (int q = 0; q < 4; ++q)
#pragma unroll
            for (int i = 0; i < 4; ++i) V[q][i] = __expf(al[q][i] - mx);
    }

    const unsigned char* Fbase = Flds + half * FBYTES + rlo * SROW + h * 8;

    if (fwd) {
#pragma unroll
        for (int s = 0; s < CLT; ++s) {
            half4_t Fh[4];
#pragma unroll
            for (int q = 0; q < 4; ++q)
                Fh[q] = *(const half4_t*)(Fbase + s * SSLAB + q * 32);
            half4_t Xh[4];
#pragma unroll
            for (int kc = 0; kc < 4; ++kc)
                Xh[kc] = pack4(V[kc][0], V[kc][1], V[kc][2], V[kc][3]);
            f32x4_t Y[4];
#pragma unroll
            for (int q = 0; q < 4; ++q) {
                f32x4_t a0 = {0.0f, 0.0f, 0.0f, 0.0f};
                f32x4_t a1 = {0.0f, 0.0f, 0.0f, 0.0f};
                a0 = __builtin_amdgcn_mfma_f32_16x16x16f16(A[q][0], Xh[0], a0, 0, 0, 0);
                a0 = __builtin_amdgcn_mfma_f32_16x16x16f16(A[q][1], Xh[1], a0, 0, 0, 0);
                a1 = __builtin_amdgcn_mfma_f32_16x16x16f16(A[q][2], Xh[2], a1, 0, 0, 0);
                a1 = __builtin_amdgcn_mfma_f32_16x16x16f16(A[q][3], Xh[3], a1, 0, 0, 0);
                Y[q] = a0 + a1;
            }
            int mt = (mbits >> s) & 1;
#pragma unroll
            for (int q = 0; q < 4; ++q)
#pragma unroll
                for (int i = 0; i < 4; ++i) {
                    float w = Y[q][i] * (float)Fh[q][i];
                    V[q][i] = mt ? w : V[q][i];
                }
        }
    } else {
#pragma unroll
        for (int s = CLT - 1; s >= 0; --s) {
            half4_t Fh[4];
#pragma unroll
            for (int kc = 0; kc < 4; ++kc)
                Fh[kc] = *(const half4_t*)(Fbase + s * SSLAB + kc * 32);
            half4_t Xh[4];
#pragma unroll
            for (int kc = 0; kc < 4; ++kc)
                Xh[kc] = pack4(V[kc][0] * (float)Fh[kc][0],
                               V[kc][1] * (float)Fh[kc][1],
                               V[kc][2] * (float)Fh[kc][2],
                               V[kc][3] * (float)Fh[kc][3]);
            f32x4_t Y[4];
#pragma unroll
            for (int q = 0; q < 4; ++q) {
                f32x4_t a0 = {0.0f, 0.0f, 0.0f, 0.0f};
                f32x4_t a1 = {0.0f, 0.0f, 0.0f, 0.0f};
                a0 = __builtin_amdgcn_mfma_f32_16x16x16f16(A[q][0], Xh[0], a0, 0, 0, 0);
                a0 = __builtin_amdgcn_mfma_f32_16x16x16f16(A[q][1], Xh[1], a0, 0, 0, 0);
                a1 = __builtin_amdgcn_mfma_f32_16x16x16f16(A[q][2], Xh[2], a1, 0, 0, 0);
                a1 = __builtin_amdgcn_mfma_f32_16x16x16f16(A[q][3], Xh[3], a1, 0, 0, 0);
                Y[q] = a0 + a1;
            }
            int mt = (mbits >> s) & 1;
#pragma unroll
            for (int q = 0; q < 4; ++q)
#pragma unroll
                for (int i = 0; i < 4; ++i)
                    V[q][i] = mt ? Y[q][i] : V[q][i];
        }
    }

    // ---- epilogue: transposed junction reduction (per superchunk half) ----
    __syncthreads();                       // all Flds (staging) reads done
    float* Rarr = (float*)(Flds + half * FBYTES);   // [16][RWS]
    float* Warr = Rarr + 16 * RWS;
    {
        float* dst = (fwd ? Rarr : Warr) + rlo * RWS + 4 * h;
#pragma unroll
        for (int q = 0; q < 4; ++q) *(f32x4_t*)(dst + 16 * q) = V[q];
    }
    __syncthreads();

    if (fwd) {
        // quad per junction: c = lane>>2 in [0,15], sub = lane&3 covers 16 elems
        const int c   = lane >> 2;
        const int sub = lane & 3;
        float dot = 0.0f, rho = 0.0f;
        {
            const float* br = Rarr + (c == 0 ? 0 : (c - 1)) * RWS + sub * 16;
            const float* bw = Warr + c * RWS + sub * 16;
#pragma unroll
            for (int u = 0; u < 4; ++u) {
                f32x4_t rv = *(const f32x4_t*)(br + 4 * u);
                f32x4_t wv = *(const f32x4_t*)(bw + 4 * u);
#pragma unroll
                for (int i = 0; i < 4; ++i) {
                    dot = fmaf(rv[i], wv[i], dot);
                    rho += wv[i];
                }
            }
        }
        dot += dpp_xor1(dot); dot += dpp_xor2(dot);
        rho += dpp_xor1(rho); rho += dpp_xor2(rho);

        float part = 0.0f;
        if (c >= 1 && sub == 0) part = __logf(dot) - __logf(rho);
        if (h == 0) part += C;             // per-run Cf (16 runs at lanes 0..15)
        float tot = wave_red_sum(part);
        if (lane == 0) Jpart[b * NG + g] = tot;

        if (rlo == 15) {
            float* dst = rB + ((size_t)b * NG + g) * 64 + 4 * h;
#pragma unroll
            for (int q = 0; q < 4; ++q) *(f32x4_t*)(dst + 16 * q) = V[q];
        }
    } else {
        if (rlo == 0) {
            float* dst = wB + ((size_t)b * NG + g) * 64 + 4 * h;
#pragma unroll
            for (int q = 0; q < 4; ++q) *(f32x4_t*)(dst + 16 * q) = V[q];
        }
    }
}

// ---------------------------------------------------------------------------
// Glue (fused final): per batch, transposed boundary junctions + end-term +
// Jpart sum -> diff[b] = numtrans[b] - den[b]. Last-finished block (int
// atomic counter) sums all 256 diffs in fixed order -> out[0]. Deterministic.
// ---------------------------------------------------------------------------
__global__ __launch_bounds__(64) void crf_glue_kernel(
    const float* __restrict__ rB,
    const float* __restrict__ wB,
    const float* __restrict__ Jpart,
    const float* __restrict__ endT,
    const float* __restrict__ numtrans,
    float* __restrict__ diffs,   // [BSZ]
    int*   __restrict__ counter, // zeroed by memsetAsync each call
    float* __restrict__ out)
{
    const int b    = blockIdx.x;
    const int lane = threadIdx.x;
    const int c    = lane >> 2;    // quad id: 0 = end-term, 1..15 = junctions
    const int sub  = lane & 3;

    float dot = 0.0f, rho = 0.0f;
    if (c == 0) {
        // end-term: fin = sum_j rB[NG-1][j] * exp(endT[j])
        const float* br = rB + ((size_t)b * NG + NG - 1) * 64 + sub * 16;
#pragma unroll
        for (int u = 0; u < 4; ++u) {
            f32x4_t rv = *(const f32x4_t*)(br + 4 * u);
            f32x4_t ev = *(const f32x4_t*)(endT + sub * 16 + 4 * u);
#pragma unroll
            for (int i = 0; i < 4; ++i) dot = fmaf(rv[i], __expf(ev[i]), dot);
        }
    } else {
        const float* br = rB + ((size_t)b * NG + c - 1) * 64 + sub * 16;
        const float* bw = wB + ((size_t)b * NG + c) * 64 + sub * 16;
#pragma unroll
        for (int u = 0; u < 4; ++u) {
            f32x4_t rv = *(const f32x4_t*)(br + 4 * u);
            f32x4_t wv = *(const f32x4_t*)(bw + 4 * u);
#pragma unroll
            for (int i = 0; i < 4; ++i) {
                dot = fmaf(rv[i], wv[i], dot);
                rho += wv[i];
            }
        }
    }
    dot += dpp_xor1(dot); dot += dpp_xor2(dot);
    rho += dpp_xor1(rho); rho += dpp_xor2(rho);

    float part = 0.0f;
    if (sub == 0) {
        part = (c == 0) ? __logf(dot) : (__logf(dot) - __logf(rho));
    }
    float contrib = part + ((lane < NG) ? Jpart[b * NG + lane] : 0.0f);
    float den = wave_red_sum(contrib);

    __shared__ int slast;
    if (lane == 0) {
        diffs[b] = numtrans[b] - den;
        __threadfence();
        int old = atomicAdd(counter, 1);
        slast = (old == BSZ - 1) ? 1 : 0;
    }
    __syncthreads();
    if (slast) {
        __threadfence();   // acquire: other blocks' diffs visible
        float x = diffs[lane] + diffs[lane + 64] +
                  diffs[lane + 128] + diffs[lane + 192];
        float tot = wave_red_sum(x);
        if (lane == 0) out[0] = tot;
    }
}

// ---------------------------------------------------------------------------
extern "C" void kernel_launch(void* const* d_in, const int* in_sizes, int n_in,
                              void* d_out, int out_size, void* d_ws, size_t ws_size,
                              hipStream_t stream)
{
    const float* logits = (const float*)d_in[0];
    const int*   tags   = (const int*)  d_in[1];
    const int*   mask   = (const int*)  d_in[2];
    const float* trans  = (const float*)d_in[3];
    const float* startT = (const float*)d_in[4];
    const float* endT   = (const float*)d_in[5];
    float* out = (float*)d_out;
    float* ws  = (float*)d_ws;

    float*   numtrans = ws;                                  // BSZ
    float*   diffs    = ws + BSZ;                            // BSZ
    float*   Jpart    = ws + 2 * BSZ;                        // BSZ*NG
    float*   rB       = Jpart + (size_t)BSZ * NG;            // BSZ*NG*64
    float*   wB       = rB + (size_t)BSZ * NG * 64;          // BSZ*NG*64
    half4_t* EtabF    = (half4_t*)(wB + (size_t)BSZ * NG * 64);  // 1024 half4
    half4_t* EtabB    = EtabF + 1024;                        // 1024 half4
    int*     counter  = (int*)(EtabB + 1024);                // 1

    hipMemsetAsync(counter, 0, sizeof(int), stream);
    crf_pre_kernel<<<1, 128, 0, stream>>>(trans, EtabF, EtabB);
    crf_fat_kernel<<<BSZ + BSZ * NP, 256, 0, stream>>>(
        logits, tags, mask, trans, startT, endT, EtabF, EtabB, rB, wB, Jpart, numtrans);
    crf_glue_kernel<<<BSZ, 64, 0, stream>>>(rB, wB, Jpart, endT, numtrans,
                                            diffs, counter, out);
}

// Round 19
// 55.632 us; speedup vs baseline: 1.2817x; 1.0345x over previous
//
#include <hip/hip_runtime.h>

#define BSZ 256
#define SEQ 2048
#define NT  64
#define KS  5.0f

#define CLT 8                     // steps per chunk
#define SC  (16 * CLT)            // steps per superchunk = 128
#define NG  (SEQ / SC)            // superchunks per sequence = 16

#define SROW  136                 // LDS bytes per (s,k) row: 64 f16 + 8 pad
#define SSLAB (16 * SROW + 8)     // LDS bytes per s-slab (16 runs) + pad
#define RWS   68                  // r/w LDS row stride in floats

typedef __fp16 half2_t __attribute__((ext_vector_type(2)));
typedef __fp16 half4_t __attribute__((ext_vector_type(4)));
typedef float  f32x4_t __attribute__((ext_vector_type(4)));
typedef int    int2_t  __attribute__((ext_vector_type(2)));

static __device__ __forceinline__ float wave_red_sum(float x) {
#pragma unroll
    for (int d = 1; d < 64; d <<= 1) x += __shfl_xor(x, d);
    return x;
}

// intra-quad xor-1 / xor-2 via DPP quad_perm (pure VALU, no LDS pipe)
static __device__ __forceinline__ float dpp_xor1(float v) {
    return __builtin_bit_cast(float,
        __builtin_amdgcn_update_dpp(0, __builtin_bit_cast(int, v), 0xB1, 0xF, 0xF, true));
}
static __device__ __forceinline__ float dpp_xor2(float v) {
    return __builtin_bit_cast(float,
        __builtin_amdgcn_update_dpp(0, __builtin_bit_cast(int, v), 0x4E, 0xF, 0xF, true));
}

static __device__ __forceinline__ half4_t pack4(float a, float b, float c, float d) {
    half2_t lo = __builtin_amdgcn_cvt_pkrtz(a, b);
    half2_t hi = __builtin_amdgcn_cvt_pkrtz(c, d);
    int2_t t;
    t.x = __builtin_bit_cast(int, lo);
    t.y = __builtin_bit_cast(int, hi);
    return __builtin_bit_cast(half4_t, t);
}

// ---------------------------------------------------------------------------
// Pre-kernel: f16 A-fragment tables. EtabF = E^T (fwd), EtabB = E (bwd).
// ---------------------------------------------------------------------------
__global__ __launch_bounds__(128) void crf_pre_kernel(
    const float* __restrict__ trans,
    half4_t* __restrict__ EtabF,
    half4_t* __restrict__ EtabB)
{
    for (int e = threadIdx.x; e < 1024; e += 128) {
        int lane = e & 63, slot = e >> 6;
        int q = slot >> 2, kc = slot & 3;
        int rlo = lane & 15, h = lane >> 4;
        int m = 16 * q + rlo;
        float f[4], bb[4];
#pragma unroll
        for (int i = 0; i < 4; ++i) {
            int k = 16 * kc + 4 * h + i;
            f[i]  = __expf(trans[k * NT + m]);
            bb[i] = __expf(trans[m * NT + k]);
        }
        EtabF[e] = pack4(f[0], f[1], f[2], f[3]);
        EtabB[e] = pack4(bb[0], bb[1], bb[2], bb[3]);
    }
}

// ---------------------------------------------------------------------------
// Fat kernel (128 threads). Blocks [0,BSZ): numerator. Blocks [BSZ,...):
// pass1 per (batch, superchunk): stage F->LDS with ALL 16 loads issued
// before any conversion (single exposed HBM latency); A-frags + maskbits
// loaded in the same shadow. Wave0 16 fwd runs, wave1 16 bwd runs (MFMA
// chains, no renorm; Cf = KS*popcount); transposed DPP junction epilogue;
// boundary r/w vectors to global.
// ---------------------------------------------------------------------------
__global__ __launch_bounds__(128) void crf_fat_kernel(
    const float* __restrict__ logits,
    const int*   __restrict__ tags,
    const int*   __restrict__ mask,
    const float* __restrict__ trans,
    const float* __restrict__ startT,
    const float* __restrict__ endT,
    const half4_t* __restrict__ EtabF,
    const half4_t* __restrict__ EtabB,
    float* __restrict__ rB,      // [BSZ][NG][64]
    float* __restrict__ wB,      // [BSZ][NG][64]
    float* __restrict__ Jpart,   // [BSZ][NG]
    float* __restrict__ numtrans)
{
    __shared__ __align__(16) unsigned char Flds[CLT * SSLAB];
    __shared__ int lmbits[16];

    if (blockIdx.x < BSZ) {
        // ---------------- numerator branch ----------------
        const int b   = blockIdx.x;
        const int tid = threadIdx.x;
        float* redf = (float*)Flds;
        int*   redi = (int*)(Flds + 512);

        const int*   __restrict__ tg = tags + (size_t)b * SEQ;
        const int*   __restrict__ mk = mask + (size_t)b * SEQ;
        const float* __restrict__ Lr = logits + (size_t)b * SEQ * NT;

        float acc = 0.0f;
        int   cnt = 0;
        for (int t = tid; t < SEQ; t += 128) {
            int mt  = mk[t];
            cnt += mt;
            int tgt = tg[t] * mt;
            if (t < SEQ - 1) {
                int m1 = mk[t + 1];
                acc += trans[tgt * NT + tg[t + 1] * m1] * (float)m1;
                acc += Lr[t * NT + tgt] * (float)mt;
            }
        }
        redf[tid] = acc;
        redi[tid] = cnt;
        __syncthreads();
        for (int off = 64; off > 0; off >>= 1) {
            if (tid < off) {
                redf[tid] += redf[tid + off];
                redi[tid] += redi[tid + off];
            }
            __syncthreads();
        }
        if (tid == 0) {
            int   last_idx = redi[0] - 1;
            int   m_last   = mk[SEQ - 1];
            int   tag0     = tg[0] * mk[0];
            int   last_tag = tg[last_idx] * mk[last_idx];
            float r = redf[0] + startT[tag0] + endT[last_tag];
            r += Lr[(size_t)(SEQ - 1) * NT + last_tag] * (float)m_last;
            numtrans[b] = r;
        }
        return;
    }

    // ---------------- pass1 branch ----------------
    const int blk  = blockIdx.x - BSZ;
    const int b    = blk / NG;
    const int g    = blk % NG;
    const int tid  = threadIdx.x;
    const bool fwd = (tid >> 6) == 0;
    const int lane = tid & 63;
    const int rlo  = lane & 15;     // run (sub-chunk) index
    const int h    = lane >> 4;

    // ---- issue maskbits + A-frag loads first (resolve under stage shadow) --
    int bits = 0;
    if (tid < 16) {
        const int* mk = mask + (size_t)b * SEQ + (size_t)g * SC + tid * CLT;
        int4 m0 = *(const int4*)(mk);
        int4 m1 = *(const int4*)(mk + 4);
        bits = (m0.x ? 1 : 0) | (m0.y ? 2 : 0) | (m0.z ? 4 : 0) | (m0.w ? 8 : 0)
             | (m1.x ? 16 : 0) | (m1.y ? 32 : 0) | (m1.z ? 64 : 0) | (m1.w ? 128 : 0);
        if (g == 0 && tid == 0) bits &= ~1;   // t=0 is the init, not a D-step
    }
    const half4_t* __restrict__ Et = fwd ? EtabF : EtabB;
    half4_t A[4][4];
#pragma unroll
    for (int q = 0; q < 4; ++q)
#pragma unroll
        for (int kc = 0; kc < 4; ++kc)
            A[q][kc] = Et[(q * 4 + kc) * 64 + lane];

    // ---- stage F (f16) into LDS: ALL 16 loads in flight, then convert ----
    const float* __restrict__ Lg = logits + ((size_t)b * SEQ + (size_t)g * SC) * NT;
    {
        f32x4_t xb[16];
#pragma unroll
        for (int jj = 0; jj < 16; ++jj) {
            int gci = jj * 128 + tid;
            xb[jj] = *(const f32x4_t*)(Lg + (size_t)(gci >> 4) * NT + (gci & 15) * 4);
        }
#pragma unroll
        for (int jj = 0; jj < 16; ++jj) {
            int gci = jj * 128 + tid;
            int row = gci >> 4;
            int col = gci & 15;
            int k   = row / CLT;
            int s   = row % CLT;
            half2_t p0 = __builtin_amdgcn_cvt_pkrtz(__expf(xb[jj][0] - KS), __expf(xb[jj][1] - KS));
            half2_t p1 = __builtin_amdgcn_cvt_pkrtz(__expf(xb[jj][2] - KS), __expf(xb[jj][3] - KS));
            int2_t w;
            w.x = __builtin_bit_cast(int, p0);
            w.y = __builtin_bit_cast(int, p1);
            *(int2_t*)(Flds + s * SSLAB + k * SROW + col * 8) = w;
        }
    }
    if (tid < 16) lmbits[tid] = bits;

    __syncthreads();

    const int mbits = lmbits[rlo];
    f32x4_t V[4];
    float C = KS * (float)__builtin_popcount(mbits);   // Cf, no renorm needed
#pragma unroll
    for (int q = 0; q < 4; ++q)
#pragma unroll
        for (int i = 0; i < 4; ++i) V[q][i] = 1.0f;

    if (fwd && g == 0 && rlo == 0) {
        // true init for global chunk 0: alpha0 = start + em(t=0)
        float mx = -1e30f;
        f32x4_t al[4];
#pragma unroll
        for (int q = 0; q < 4; ++q) {
            f32x4_t em = *(const f32x4_t*)(logits + (size_t)b * SEQ * NT + 16 * q + 4 * h);
            f32x4_t st = *(const f32x4_t*)(startT + 16 * q + 4 * h);
#pragma unroll
            for (int i = 0; i < 4; ++i) {
                al[q][i] = st[i] + em[i];
                mx = fmaxf(mx, al[q][i]);
            }
        }
        mx = fmaxf(mx, __shfl_xor(mx, 16));
        mx = fmaxf(mx, __shfl_xor(mx, 32));
        C += mx;
#pragma unroll
        for (int q = 0; q < 4; ++q)
#pragma unroll
            for (int i = 0; i < 4; ++i) V[q][i] = __expf(al[q][i] - mx);
    }

    const unsigned char* Fbase = Flds + rlo * SROW + h * 8;

    if (fwd) {
#pragma unroll
        for (int s = 0; s < CLT; ++s) {
            half4_t Fh[4];
#pragma unroll
            for (int q = 0; q < 4; ++q)
                Fh[q] = *(const half4_t*)(Fbase + s * SSLAB + q * 32);
            half4_t Xh[4];
#pragma unroll
            for (int kc = 0; kc < 4; ++kc)
                Xh[kc] = pack4(V[kc][0], V[kc][1], V[kc][2], V[kc][3]);
            f32x4_t Y[4];
#pragma unroll
            for (int q = 0; q < 4; ++q) {
                f32x4_t a0 = {0.0f, 0.0f, 0.0f, 0.0f};
                f32x4_t a1 = {0.0f, 0.0f, 0.0f, 0.0f};
                a0 = __builtin_amdgcn_mfma_f32_16x16x16f16(A[q][0], Xh[0], a0, 0, 0, 0);
                a0 = __builtin_amdgcn_mfma_f32_16x16x16f16(A[q][1], Xh[1], a0, 0, 0, 0);
                a1 = __builtin_amdgcn_mfma_f32_16x16x16f16(A[q][2], Xh[2], a1, 0, 0, 0);
                a1 = __builtin_amdgcn_mfma_f32_16x16x16f16(A[q][3], Xh[3], a1, 0, 0, 0);
                Y[q] = a0 + a1;
            }
            int mt = (mbits >> s) & 1;
#pragma unroll
            for (int q = 0; q < 4; ++q)
#pragma unroll
                for (int i = 0; i < 4; ++i) {
                    float w = Y[q][i] * (float)Fh[q][i];
                    V[q][i] = mt ? w : V[q][i];
                }
        }
    } else {
#pragma unroll
        for (int s = CLT - 1; s >= 0; --s) {
            half4_t Fh[4];
#pragma unroll
            for (int kc = 0; kc < 4; ++kc)
                Fh[kc] = *(const half4_t*)(Fbase + s * SSLAB + kc * 32);
            half4_t Xh[4];
#pragma unroll
            for (int kc = 0; kc < 4; ++kc)
                Xh[kc] = pack4(V[kc][0] * (float)Fh[kc][0],
                               V[kc][1] * (float)Fh[kc][1],
                               V[kc][2] * (float)Fh[kc][2],
                               V[kc][3] * (float)Fh[kc][3]);
            f32x4_t Y[4];
#pragma unroll
            for (int q = 0; q < 4; ++q) {
                f32x4_t a0 = {0.0f, 0.0f, 0.0f, 0.0f};
                f32x4_t a1 = {0.0f, 0.0f, 0.0f, 0.0f};
                a0 = __builtin_amdgcn_mfma_f32_16x16x16f16(A[q][0], Xh[0], a0, 0, 0, 0);
                a0 = __builtin_amdgcn_mfma_f32_16x16x16f16(A[q][1], Xh[1], a0, 0, 0, 0);
                a1 = __builtin_amdgcn_mfma_f32_16x16x16f16(A[q][2], Xh[2], a1, 0, 0, 0);
                a1 = __builtin_amdgcn_mfma_f32_16x16x16f16(A[q][3], Xh[3], a1, 0, 0, 0);
                Y[q] = a0 + a1;
            }
            int mt = (mbits >> s) & 1;
#pragma unroll
            for (int q = 0; q < 4; ++q)
#pragma unroll
                for (int i = 0; i < 4; ++i)
                    V[q][i] = mt ? Y[q][i] : V[q][i];
        }
    }

    // ---- epilogue: transposed junction reduction ----
    __syncthreads();                       // all Flds (staging) reads done
    float* Rarr = (float*)Flds;            // [16][RWS]
    float* Warr = Rarr + 16 * RWS;
    {
        float* dst = (fwd ? Rarr : Warr) + rlo * RWS + 4 * h;
#pragma unroll
        for (int q = 0; q < 4; ++q) *(f32x4_t*)(dst + 16 * q) = V[q];
    }
    __syncthreads();

    if (fwd) {
        // quad per junction: c = lane>>2 in [0,15], sub = lane&3 covers 16 elems
        const int c   = lane >> 2;
        const int sub = lane & 3;
        float dot = 0.0f, rho = 0.0f;
        {
            const float* br = Rarr + (c == 0 ? 0 : (c - 1)) * RWS + sub * 16;
            const float* bw = Warr + c * RWS + sub * 16;
#pragma unroll
            for (int u = 0; u < 4; ++u) {
                f32x4_t rv = *(const f32x4_t*)(br + 4 * u);
                f32x4_t wv = *(const f32x4_t*)(bw + 4 * u);
#pragma unroll
                for (int i = 0; i < 4; ++i) {
                    dot = fmaf(rv[i], wv[i], dot);
                    rho += wv[i];
                }
            }
        }
        dot += dpp_xor1(dot); dot += dpp_xor2(dot);
        rho += dpp_xor1(rho); rho += dpp_xor2(rho);

        float part = 0.0f;
        if (c >= 1 && sub == 0) part = __logf(dot) - __logf(rho);
        if (h == 0) part += C;             // per-run Cf (16 runs at lanes 0..15)
        float tot = wave_red_sum(part);
        if (lane == 0) Jpart[b * NG + g] = tot;

        if (rlo == 15) {
            float* dst = rB + ((size_t)b * NG + g) * 64 + 4 * h;
#pragma unroll
            for (int q = 0; q < 4; ++q) *(f32x4_t*)(dst + 16 * q) = V[q];
        }
    } else {
        if (rlo == 0) {
            float* dst = wB + ((size_t)b * NG + g) * 64 + 4 * h;
#pragma unroll
            for (int q = 0; q < 4; ++q) *(f32x4_t*)(dst + 16 * q) = V[q];
        }
    }
}

// ---------------------------------------------------------------------------
// Glue (fused final): per batch, transposed boundary junctions + end-term +
// Jpart sum -> diff[b] = numtrans[b] - den[b]. Last-finished block (int
// atomic counter) sums all 256 diffs in fixed order -> out[0]. Deterministic.
// ---------------------------------------------------------------------------
__global__ __launch_bounds__(64) void crf_glue_kernel(
    const float* __restrict__ rB,
    const float* __restrict__ wB,
    const float* __restrict__ Jpart,
    const float* __restrict__ endT,
    const float* __restrict__ numtrans,
    float* __restrict__ diffs,   // [BSZ]
    int*   __restrict__ counter, // zeroed by memsetAsync each call
    float* __restrict__ out)
{
    const int b    = blockIdx.x;
    const int lane = threadIdx.x;
    const int c    = lane >> 2;    // quad id: 0 = end-term, 1..15 = junctions
    const int sub  = lane & 3;

    float dot = 0.0f, rho = 0.0f;
    if (c == 0) {
        // end-term: fin = sum_j rB[NG-1][j] * exp(endT[j])
        const float* br = rB + ((size_t)b * NG + NG - 1) * 64 + sub * 16;
#pragma unroll
        for (int u = 0; u < 4; ++u) {
            f32x4_t rv = *(const f32x4_t*)(br + 4 * u);
            f32x4_t ev = *(const f32x4_t*)(endT + sub * 16 + 4 * u);
#pragma unroll
            for (int i = 0; i < 4; ++i) dot = fmaf(rv[i], __expf(ev[i]), dot);
        }
    } else {
        const float* br = rB + ((size_t)b * NG + c - 1) * 64 + sub * 16;
        const float* bw = wB + ((size_t)b * NG + c) * 64 + sub * 16;
#pragma unroll
        for (int u = 0; u < 4; ++u) {
            f32x4_t rv = *(const f32x4_t*)(br + 4 * u);
            f32x4_t wv = *(const f32x4_t*)(bw + 4 * u);
#pragma unroll
            for (int i = 0; i < 4; ++i) {
                dot = fmaf(rv[i], wv[i], dot);
                rho += wv[i];
            }
        }
    }
    dot += dpp_xor1(dot); dot += dpp_xor2(dot);
    rho += dpp_xor1(rho); rho += dpp_xor2(rho);

    float part = 0.0f;
    if (sub == 0) {
        part = (c == 0) ? __logf(dot) : (__logf(dot) - __logf(rho));
    }
    float contrib = part + ((lane < NG) ? Jpart[b * NG + lane] : 0.0f);
    float den = wave_red_sum(contrib);

    __shared__ int slast;
    if (lane == 0) {
        diffs[b] = numtrans[b] - den;
        __threadfence();
        int old = atomicAdd(counter, 1);
        slast = (old == BSZ - 1) ? 1 : 0;
    }
    __syncthreads();
    if (slast) {
        __threadfence();   // acquire: other blocks' diffs visible
        float x = diffs[lane] + diffs[lane + 64] +
                  diffs[lane + 128] + diffs[lane + 192];
        float tot = wave_red_sum(x);
        if (lane == 0) out[0] = tot;
    }
}

// ---------------------------------------------------------------------------
extern "C" void kernel_launch(void* const* d_in, const int* in_sizes, int n_in,
                              void* d_out, int out_size, void* d_ws, size_t ws_size,
                              hipStream_t stream)
{
    const float* logits = (const float*)d_in[0];
    const int*   tags   = (const int*)  d_in[1];
    const int*   mask   = (const int*)  d_in[2];
    const float* trans  = (const float*)d_in[3];
    const float* startT = (const float*)d_in[4];
    const float* endT   = (const float*)d_in[5];
    float* out = (float*)d_out;
    float* ws  = (float*)d_ws;

    float*   numtrans = ws;                                  // BSZ
    float*   diffs    = ws + BSZ;                            // BSZ
    float*   Jpart    = ws + 2 * BSZ;                        // BSZ*NG
    float*   rB       = Jpart + (size_t)BSZ * NG;            // BSZ*NG*64
    float*   wB       = rB + (size_t)BSZ * NG * 64;          // BSZ*NG*64
    half4_t* EtabF    = (half4_t*)(wB + (size_t)BSZ * NG * 64);  // 1024 half4
    half4_t* EtabB    = EtabF + 1024;                        // 1024 half4
    int*     counter  = (int*)(EtabB + 1024);                // 1

    hipMemsetAsync(counter, 0, sizeof(int), stream);
    crf_pre_kernel<<<1, 128, 0, stream>>>(trans, EtabF, EtabB);
    crf_fat_kernel<<<BSZ + BSZ * NG, 128, 0, stream>>>(
        logits, tags, mask, trans, startT, endT, EtabF, EtabB, rB, wB, Jpart, numtrans);
    crf_glue_kernel<<<BSZ, 64, 0, stream>>>(rB, wB, Jpart, endT, numtrans,
                                            diffs, counter, out);
}